// Round 13
// baseline (529.317 us; speedup 1.0000x reference)
//
#include <hip/hip_runtime.h>
#include <hip/hip_bf16.h>

// 2-layer GCN: norm (self-loops, sym D^-1/2), CSR build, GEMM, gather-aggregate.
// R10 (3rd resubmit — broker timeouts): fold dinv into GEMM output (g =
// dinv*(x@W), bf16) so per-edge work is a pure gather+add and CSR is plain int
// rows (4B/edge). agg = dinv[c]*(g[c]+sum). 16x unroll (16 gathers in flight,
// 4 accumulators). 256-thread agg blocks (R8: 1024 regresses). f32 accumulate.

static inline int cdiv(int a, int b) { return (a + b - 1) / b; }

__device__ inline unsigned short f2bf(float f) {
    __hip_bfloat16 b = __float2bfloat16(f);
    return *(unsigned short*)&b;
}
__device__ inline float2 bf2_to_f2(unsigned int u) {
    return make_float2(__uint_as_float(u << 16),
                       __uint_as_float(u & 0xffff0000u));
}
__device__ inline float bf_to_f(unsigned short u) {
    return __uint_as_float(((unsigned int)u) << 16);
}

// ---------------- CSR build ----------------

__global__ void k_init(int* __restrict__ cnt, int* __restrict__ cursor, int n) {
    int i = blockIdx.x * blockDim.x + threadIdx.x;
    if (i < n) { cnt[i] = 0; cursor[i] = 0; }
}

__global__ void k_deg(const int* __restrict__ col, int* __restrict__ cnt, int e) {
    int i = blockIdx.x * blockDim.x + threadIdx.x;
    if (i < e) atomicAdd(&cnt[col[i]], 1);
}

__global__ void k_dinv(const int* __restrict__ cnt, float* __restrict__ dinv, int n) {
    int i = blockIdx.x * blockDim.x + threadIdx.x;
    if (i < n) dinv[i] = rsqrtf((float)(cnt[i] + 1));  // +1 self-loop, always > 0
}

__global__ void k_scan1(const int* __restrict__ cnt, int* __restrict__ pref,
                        int* __restrict__ bsum, int n) {
    __shared__ int s[256];
    int t = threadIdx.x;
    int i = blockIdx.x * 256 + t;
    int v = (i < n) ? cnt[i] : 0;
    s[t] = v;
    __syncthreads();
    for (int off = 1; off < 256; off <<= 1) {
        int x = (t >= off) ? s[t - off] : 0;
        __syncthreads();
        s[t] += x;
        __syncthreads();
    }
    if (i < n) pref[i] = s[t] - v;  // exclusive within block
    if (t == 255) bsum[blockIdx.x] = s[255];
}

__global__ void k_scan2(const int* __restrict__ bsum, int* __restrict__ boff, int nb) {
    __shared__ int s[512];
    int t = threadIdx.x;
    int v = (t < nb) ? bsum[t] : 0;
    s[t] = v;
    __syncthreads();
    for (int off = 1; off < 512; off <<= 1) {
        int x = (t >= off) ? s[t - off] : 0;
        __syncthreads();
        s[t] += x;
        __syncthreads();
    }
    if (t < nb) boff[t] = s[t] - v;  // exclusive
}

__global__ void k_scan3(int* __restrict__ pref, const int* __restrict__ boff,
                        int n, int e_total) {
    int i = blockIdx.x * blockDim.x + threadIdx.x;
    if (i < n) pref[i] += boff[i >> 8];
    if (i == n) pref[n] = e_total;
}

__global__ void k_fill(const int* __restrict__ row, const int* __restrict__ col,
                       const int* __restrict__ indptr, int* __restrict__ cursor,
                       int* __restrict__ csr_row, int e) {
    int i = blockIdx.x * blockDim.x + threadIdx.x;
    if (i >= e) return;
    int c = col[i];
    int pos = indptr[c] + atomicAdd(&cursor[c], 1);
    csr_row[pos] = row[i];
}

// ------- dense GEMM: G[n][COUT] = dinv[n] * (X[n][128] @ W[128][COUT]), bf16 out -------

template <int COUT>
__global__ __launch_bounds__(256) void gemm_k(const float* __restrict__ X,
                                              const float* __restrict__ W,
                                              const float* __restrict__ dinv,
                                              __hip_bfloat16* __restrict__ G, int n) {
    constexpr int KT = 64;             // k-tile
    constexpr int CG = COUT / 4;       // thread groups along channels
    constexpr int MG = 256 / CG;       // thread groups along rows
    constexpr int TILE_M = MG * 4;
    __shared__ float xs[TILE_M][KT];
    __shared__ float ws[KT][COUT];
    const int t = threadIdx.x;
    const int m_base = blockIdx.x * TILE_M;
    const int tx = t % CG, ty = t / CG;
    const int c0 = tx * 4, m0 = ty * 4;
    float acc[4][4] = {};
    for (int kt = 0; kt < 128; kt += KT) {
        {   // stage W tile (KT x COUT), linear copy
            const float4* src = (const float4*)(W + (size_t)kt * COUT);
            float4* dst = (float4*)&ws[0][0];
            constexpr int NW = KT * COUT / 4 / 256;
#pragma unroll
            for (int i = 0; i < NW; i++) dst[t + i * 256] = src[t + i * 256];
        }
        {   // stage X tile (TILE_M x KT)
            float4* dst = (float4*)&xs[0][0];
            constexpr int NX = TILE_M * KT / 4 / 256;
#pragma unroll
            for (int i = 0; i < NX; i++) {
                int idx = t + i * 256;
                int m = idx >> 4, q = idx & 15;  // 16 float4 per row of KT
                int gm = m_base + m;
                float4 v = make_float4(0.f, 0.f, 0.f, 0.f);
                if (gm < n) v = ((const float4*)X)[(size_t)gm * 32 + (kt >> 2) + q];
                dst[idx] = v;
            }
        }
        __syncthreads();
#pragma unroll
        for (int k = 0; k < KT; k += 4) {
            float xr[4][4], wr[4][4];
#pragma unroll
            for (int mm = 0; mm < 4; mm++) {
                float4 v = *(const float4*)&xs[m0 + mm][k];
                xr[mm][0] = v.x; xr[mm][1] = v.y; xr[mm][2] = v.z; xr[mm][3] = v.w;
            }
#pragma unroll
            for (int kk = 0; kk < 4; kk++) {
                float4 v = *(const float4*)&ws[k + kk][c0];
                wr[kk][0] = v.x; wr[kk][1] = v.y; wr[kk][2] = v.z; wr[kk][3] = v.w;
            }
#pragma unroll
            for (int kk = 0; kk < 4; kk++)
#pragma unroll
                for (int mm = 0; mm < 4; mm++)
#pragma unroll
                    for (int cc = 0; cc < 4; cc++)
                        acc[mm][cc] = fmaf(xr[mm][kk], wr[kk][cc], acc[mm][cc]);
        }
        __syncthreads();
    }
#pragma unroll
    for (int mm = 0; mm < 4; mm++) {
        int gm = m_base + m0 + mm;
        if (gm < n) {
            float dv = dinv[gm];
            ushort4 o;
            o.x = f2bf(dv * acc[mm][0]); o.y = f2bf(dv * acc[mm][1]);
            o.z = f2bf(dv * acc[mm][2]); o.w = f2bf(dv * acc[mm][3]);
            *(ushort4*)&G[(size_t)gm * COUT + c0] = o;
        }
    }
}

// -------- aggregation: one wave per node; s = g[c] + sum g[r]; out = dinv*s + b --------

// C=128: lane handles 2 channels (packed bf16x2 = 4B gather). relu.
__global__ __launch_bounds__(256) void k_agg128(const __hip_bfloat16* __restrict__ g,
                                                const int* __restrict__ indptr,
                                                const int* __restrict__ csr_row,
                                                const float* __restrict__ dinv,
                                                const float* __restrict__ bias,
                                                float* __restrict__ out, int n) {
    int wid = (blockIdx.x * blockDim.x + threadIdx.x) >> 6;
    int lane = threadIdx.x & 63;
    if (wid >= n) return;
    const unsigned int* gp = (const unsigned int*)g;  // 2 bf16 per uint, 64/row
    float2 a[4];
#pragma unroll
    for (int k = 0; k < 4; k++) a[k] = make_float2(0.f, 0.f);
    {
        float2 v = bf2_to_f2(gp[(size_t)wid * 64 + lane]);  // self (g[c])
        a[0].x = v.x; a[0].y = v.y;
    }
    int e = indptr[wid], e1 = indptr[wid + 1];
    for (; e + 16 <= e1; e += 16) {
        int r[16];
#pragma unroll
        for (int k = 0; k < 16; k++) r[k] = csr_row[e + k];
#pragma unroll
        for (int k = 0; k < 16; k++) {
            float2 v = bf2_to_f2(gp[(size_t)r[k] * 64 + lane]);
            a[k & 3].x += v.x;
            a[k & 3].y += v.y;
        }
    }
    for (; e < e1; e++) {
        int r = csr_row[e];
        float2 v = bf2_to_f2(gp[(size_t)r * 64 + lane]);
        a[0].x += v.x;
        a[0].y += v.y;
    }
    float dv = dinv[wid];
    float sx = (a[0].x + a[1].x) + (a[2].x + a[3].x);
    float sy = (a[0].y + a[1].y) + (a[2].y + a[3].y);
    float2 b = ((const float2*)bias)[lane];
    ((float2*)(out + (size_t)wid * 128))[lane] =
        make_float2(fmaxf(fmaf(dv, sx, b.x), 0.f), fmaxf(fmaf(dv, sy, b.y), 0.f));
}

// C=64: lane handles 1 channel (2B bf16 gather; 128B/row = 1 cache line).
__global__ __launch_bounds__(256) void k_agg64(const __hip_bfloat16* __restrict__ g,
                                               const int* __restrict__ indptr,
                                               const int* __restrict__ csr_row,
                                               const float* __restrict__ dinv,
                                               const float* __restrict__ bias,
                                               float* __restrict__ out, int n) {
    int wid = (blockIdx.x * blockDim.x + threadIdx.x) >> 6;
    int lane = threadIdx.x & 63;
    if (wid >= n) return;
    const unsigned short* gp = (const unsigned short*)g;
    float a[4];
#pragma unroll
    for (int k = 0; k < 4; k++) a[k] = 0.f;
    a[0] = bf_to_f(gp[(size_t)wid * 64 + lane]);  // self
    int e = indptr[wid], e1 = indptr[wid + 1];
    for (; e + 16 <= e1; e += 16) {
        int r[16];
#pragma unroll
        for (int k = 0; k < 16; k++) r[k] = csr_row[e + k];
#pragma unroll
        for (int k = 0; k < 16; k++)
            a[k & 3] += bf_to_f(gp[(size_t)r[k] * 64 + lane]);
    }
    for (; e < e1; e++)
        a[0] += bf_to_f(gp[(size_t)csr_row[e] * 64 + lane]);
    float s = (a[0] + a[1]) + (a[2] + a[3]);
    out[(size_t)wid * 64 + lane] = fmaf(dinv[wid], s, bias[lane]);
}

// ---------------- launch ----------------

extern "C" void kernel_launch(void* const* d_in, const int* in_sizes, int n_in,
                              void* d_out, int out_size, void* d_ws, size_t ws_size,
                              hipStream_t stream) {
    const float* x  = (const float*)d_in[0];
    const int* ei   = (const int*)d_in[1];
    const float* W1 = (const float*)d_in[2];
    const float* b1 = (const float*)d_in[3];
    const float* W2 = (const float*)d_in[4];
    const float* b2 = (const float*)d_in[5];
    float* out = (float*)d_out;

    const int N = in_sizes[0] / 128;
    const int E = in_sizes[1] / 2;
    const int* row = ei;       // edge_index[0] = source
    const int* col = ei + E;   // edge_index[1] = target

    char* p = (char*)d_ws;
    auto carve = [&](size_t bytes) -> void* {
        void* r = (void*)p;
        p += (bytes + 255) & ~(size_t)255;
        return r;
    };
    int*   cnt      = (int*)carve((size_t)N * 4);
    float* dinv     = (float*)carve((size_t)N * 4);
    int*   indptr   = (int*)carve((size_t)(N + 1) * 4);
    int*   bsum     = (int*)carve(512 * 4);
    int*   boff     = (int*)carve(512 * 4);
    int*   cursor   = (int*)carve((size_t)N * 4);
    int*   csr_row  = (int*)carve((size_t)E * 4);
    __hip_bfloat16* g1 = (__hip_bfloat16*)carve((size_t)N * 128 * 2);  // dinv*x@W1
    float* h1          = (float*)carve((size_t)N * 128 * 4);
    __hip_bfloat16* g2 = (__hip_bfloat16*)carve((size_t)N * 64 * 2);   // dinv*h1@W2

    const int NB = cdiv(N, 256);  // scan blocks (391 <= 512)

    k_init<<<cdiv(N, 256), 256, 0, stream>>>(cnt, cursor, N);
    k_deg<<<cdiv(E, 256), 256, 0, stream>>>(col, cnt, E);
    k_dinv<<<cdiv(N, 256), 256, 0, stream>>>(cnt, dinv, N);
    k_scan1<<<NB, 256, 0, stream>>>(cnt, indptr, bsum, N);
    k_scan2<<<1, 512, 0, stream>>>(bsum, boff, NB);
    k_scan3<<<cdiv(N + 1, 256), 256, 0, stream>>>(indptr, boff, N, E);
    k_fill<<<cdiv(E, 256), 256, 0, stream>>>(row, col, indptr, cursor, csr_row, E);

    // layer 1: g1 = bf16(dinv * x@W1) ; h1 = relu(dinv*(g1_self+sum) + b1)
    gemm_k<128><<<cdiv(N, 32), 256, 0, stream>>>(x, W1, dinv, g1, N);
    k_agg128<<<cdiv(N, 4), 256, 0, stream>>>(g1, indptr, csr_row, dinv, b1, h1, N);
    // layer 2: g2 = bf16(dinv * h1@W2) ; out = dinv*(g2_self+sum) + b2
    gemm_k<64><<<cdiv(N, 64), 256, 0, stream>>>(h1, W2, dinv, g2, N);
    k_agg64<<<cdiv(N, 4), 256, 0, stream>>>(g2, indptr, csr_row, dinv, b2, out, N);
}

// Round 14
// 489.334 us; speedup vs baseline: 1.0817x; 1.0817x over previous
//
#include <hip/hip_runtime.h>
#include <hip/hip_bf16.h>

// 2-layer GCN: norm (self-loops, sym D^-1/2), CSR build, GEMM, gather-aggregate.
// R14: keep R10's folded-dinv (g = dinv*(x@W) bf16, plain-int CSR, pure adds)
// but revert unroll to 8 with 8 accumulators 1:1 (R13 showed 16x starves VGPRs
// and serializes: 114us vs R9's 90us at 8x). Agg kernels are grid-stride
// persistent waves (8192 waves, ~12 nodes each) to kill block-churn occupancy
// loss (58-62% at 4-wave blocks across R6/R9/R13).

static inline int cdiv(int a, int b) { return (a + b - 1) / b; }

__device__ inline unsigned short f2bf(float f) {
    __hip_bfloat16 b = __float2bfloat16(f);
    return *(unsigned short*)&b;
}
__device__ inline float2 bf2_to_f2(unsigned int u) {
    return make_float2(__uint_as_float(u << 16),
                       __uint_as_float(u & 0xffff0000u));
}
__device__ inline float bf_to_f(unsigned short u) {
    return __uint_as_float(((unsigned int)u) << 16);
}

// ---------------- CSR build ----------------

__global__ void k_init(int* __restrict__ cnt, int* __restrict__ cursor, int n) {
    int i = blockIdx.x * blockDim.x + threadIdx.x;
    if (i < n) { cnt[i] = 0; cursor[i] = 0; }
}

__global__ void k_deg(const int* __restrict__ col, int* __restrict__ cnt, int e) {
    int i = blockIdx.x * blockDim.x + threadIdx.x;
    if (i < e) atomicAdd(&cnt[col[i]], 1);
}

__global__ void k_dinv(const int* __restrict__ cnt, float* __restrict__ dinv, int n) {
    int i = blockIdx.x * blockDim.x + threadIdx.x;
    if (i < n) dinv[i] = rsqrtf((float)(cnt[i] + 1));  // +1 self-loop, always > 0
}

__global__ void k_scan1(const int* __restrict__ cnt, int* __restrict__ pref,
                        int* __restrict__ bsum, int n) {
    __shared__ int s[256];
    int t = threadIdx.x;
    int i = blockIdx.x * 256 + t;
    int v = (i < n) ? cnt[i] : 0;
    s[t] = v;
    __syncthreads();
    for (int off = 1; off < 256; off <<= 1) {
        int x = (t >= off) ? s[t - off] : 0;
        __syncthreads();
        s[t] += x;
        __syncthreads();
    }
    if (i < n) pref[i] = s[t] - v;  // exclusive within block
    if (t == 255) bsum[blockIdx.x] = s[255];
}

__global__ void k_scan2(const int* __restrict__ bsum, int* __restrict__ boff, int nb) {
    __shared__ int s[512];
    int t = threadIdx.x;
    int v = (t < nb) ? bsum[t] : 0;
    s[t] = v;
    __syncthreads();
    for (int off = 1; off < 512; off <<= 1) {
        int x = (t >= off) ? s[t - off] : 0;
        __syncthreads();
        s[t] += x;
        __syncthreads();
    }
    if (t < nb) boff[t] = s[t] - v;  // exclusive
}

__global__ void k_scan3(int* __restrict__ pref, const int* __restrict__ boff,
                        int n, int e_total) {
    int i = blockIdx.x * blockDim.x + threadIdx.x;
    if (i < n) pref[i] += boff[i >> 8];
    if (i == n) pref[n] = e_total;
}

__global__ void k_fill(const int* __restrict__ row, const int* __restrict__ col,
                       const int* __restrict__ indptr, int* __restrict__ cursor,
                       int* __restrict__ csr_row, int e) {
    int i = blockIdx.x * blockDim.x + threadIdx.x;
    if (i >= e) return;
    int c = col[i];
    int pos = indptr[c] + atomicAdd(&cursor[c], 1);
    csr_row[pos] = row[i];
}

// ------- dense GEMM: G[n][COUT] = dinv[n] * (X[n][128] @ W[128][COUT]), bf16 out -------

template <int COUT>
__global__ __launch_bounds__(256) void gemm_k(const float* __restrict__ X,
                                              const float* __restrict__ W,
                                              const float* __restrict__ dinv,
                                              __hip_bfloat16* __restrict__ G, int n) {
    constexpr int KT = 64;             // k-tile
    constexpr int CG = COUT / 4;       // thread groups along channels
    constexpr int MG = 256 / CG;       // thread groups along rows
    constexpr int TILE_M = MG * 4;
    __shared__ float xs[TILE_M][KT];
    __shared__ float ws[KT][COUT];
    const int t = threadIdx.x;
    const int m_base = blockIdx.x * TILE_M;
    const int tx = t % CG, ty = t / CG;
    const int c0 = tx * 4, m0 = ty * 4;
    float acc[4][4] = {};
    for (int kt = 0; kt < 128; kt += KT) {
        {   // stage W tile (KT x COUT), linear copy
            const float4* src = (const float4*)(W + (size_t)kt * COUT);
            float4* dst = (float4*)&ws[0][0];
            constexpr int NW = KT * COUT / 4 / 256;
#pragma unroll
            for (int i = 0; i < NW; i++) dst[t + i * 256] = src[t + i * 256];
        }
        {   // stage X tile (TILE_M x KT)
            float4* dst = (float4*)&xs[0][0];
            constexpr int NX = TILE_M * KT / 4 / 256;
#pragma unroll
            for (int i = 0; i < NX; i++) {
                int idx = t + i * 256;
                int m = idx >> 4, q = idx & 15;  // 16 float4 per row of KT
                int gm = m_base + m;
                float4 v = make_float4(0.f, 0.f, 0.f, 0.f);
                if (gm < n) v = ((const float4*)X)[(size_t)gm * 32 + (kt >> 2) + q];
                dst[idx] = v;
            }
        }
        __syncthreads();
#pragma unroll
        for (int k = 0; k < KT; k += 4) {
            float xr[4][4], wr[4][4];
#pragma unroll
            for (int mm = 0; mm < 4; mm++) {
                float4 v = *(const float4*)&xs[m0 + mm][k];
                xr[mm][0] = v.x; xr[mm][1] = v.y; xr[mm][2] = v.z; xr[mm][3] = v.w;
            }
#pragma unroll
            for (int kk = 0; kk < 4; kk++) {
                float4 v = *(const float4*)&ws[k + kk][c0];
                wr[kk][0] = v.x; wr[kk][1] = v.y; wr[kk][2] = v.z; wr[kk][3] = v.w;
            }
#pragma unroll
            for (int kk = 0; kk < 4; kk++)
#pragma unroll
                for (int mm = 0; mm < 4; mm++)
#pragma unroll
                    for (int cc = 0; cc < 4; cc++)
                        acc[mm][cc] = fmaf(xr[mm][kk], wr[kk][cc], acc[mm][cc]);
        }
        __syncthreads();
    }
#pragma unroll
    for (int mm = 0; mm < 4; mm++) {
        int gm = m_base + m0 + mm;
        if (gm < n) {
            float dv = dinv[gm];
            ushort4 o;
            o.x = f2bf(dv * acc[mm][0]); o.y = f2bf(dv * acc[mm][1]);
            o.z = f2bf(dv * acc[mm][2]); o.w = f2bf(dv * acc[mm][3]);
            *(ushort4*)&G[(size_t)gm * COUT + c0] = o;
        }
    }
}

// -------- aggregation: grid-stride persistent waves, one node at a time --------
// s = g[c] + sum g[r]; out = dinv[c]*s + b. 8 gathers in flight, 8 accumulators.

// C=128: lane handles 2 channels (packed bf16x2 = 4B gather). relu.
__global__ __launch_bounds__(256) void k_agg128(const __hip_bfloat16* __restrict__ g,
                                                const int* __restrict__ indptr,
                                                const int* __restrict__ csr_row,
                                                const float* __restrict__ dinv,
                                                const float* __restrict__ bias,
                                                float* __restrict__ out, int n) {
    const int lane = threadIdx.x & 63;
    const int wid0 = (blockIdx.x * blockDim.x + threadIdx.x) >> 6;
    const int nw = (gridDim.x * blockDim.x) >> 6;
    const unsigned int* gp = (const unsigned int*)g;  // 2 bf16 per uint, 64/row
    const float2 b = ((const float2*)bias)[lane];
    for (int wid = wid0; wid < n; wid += nw) {
        float2 a[8];
#pragma unroll
        for (int k = 0; k < 8; k++) a[k] = make_float2(0.f, 0.f);
        {
            float2 v = bf2_to_f2(gp[(size_t)wid * 64 + lane]);  // self (g[c])
            a[0] = v;
        }
        int e = indptr[wid], e1 = indptr[wid + 1];
        for (; e + 8 <= e1; e += 8) {
            int r[8];
#pragma unroll
            for (int k = 0; k < 8; k++) r[k] = csr_row[e + k];
#pragma unroll
            for (int k = 0; k < 8; k++) {
                float2 v = bf2_to_f2(gp[(size_t)r[k] * 64 + lane]);
                a[k].x += v.x;
                a[k].y += v.y;
            }
        }
        for (; e < e1; e++) {
            float2 v = bf2_to_f2(gp[(size_t)csr_row[e] * 64 + lane]);
            a[0].x += v.x;
            a[0].y += v.y;
        }
        float dv = dinv[wid];
        float sx = ((a[0].x + a[1].x) + (a[2].x + a[3].x)) +
                   ((a[4].x + a[5].x) + (a[6].x + a[7].x));
        float sy = ((a[0].y + a[1].y) + (a[2].y + a[3].y)) +
                   ((a[4].y + a[5].y) + (a[6].y + a[7].y));
        ((float2*)(out + (size_t)wid * 128))[lane] =
            make_float2(fmaxf(fmaf(dv, sx, b.x), 0.f),
                        fmaxf(fmaf(dv, sy, b.y), 0.f));
    }
}

// C=64: lane handles 1 channel (2B bf16 gather; 128B/row = 1 cache line).
__global__ __launch_bounds__(256) void k_agg64(const __hip_bfloat16* __restrict__ g,
                                               const int* __restrict__ indptr,
                                               const int* __restrict__ csr_row,
                                               const float* __restrict__ dinv,
                                               const float* __restrict__ bias,
                                               float* __restrict__ out, int n) {
    const int lane = threadIdx.x & 63;
    const int wid0 = (blockIdx.x * blockDim.x + threadIdx.x) >> 6;
    const int nw = (gridDim.x * blockDim.x) >> 6;
    const unsigned short* gp = (const unsigned short*)g;
    const float b = bias[lane];
    for (int wid = wid0; wid < n; wid += nw) {
        float a[8];
#pragma unroll
        for (int k = 0; k < 8; k++) a[k] = 0.f;
        a[0] = bf_to_f(gp[(size_t)wid * 64 + lane]);  // self
        int e = indptr[wid], e1 = indptr[wid + 1];
        for (; e + 8 <= e1; e += 8) {
            int r[8];
#pragma unroll
            for (int k = 0; k < 8; k++) r[k] = csr_row[e + k];
#pragma unroll
            for (int k = 0; k < 8; k++)
                a[k] += bf_to_f(gp[(size_t)r[k] * 64 + lane]);
        }
        for (; e < e1; e++)
            a[0] += bf_to_f(gp[(size_t)csr_row[e] * 64 + lane]);
        float s = ((a[0] + a[1]) + (a[2] + a[3])) + ((a[4] + a[5]) + (a[6] + a[7]));
        out[(size_t)wid * 64 + lane] = fmaf(dinv[wid], s, b);
    }
}

// ---------------- launch ----------------

extern "C" void kernel_launch(void* const* d_in, const int* in_sizes, int n_in,
                              void* d_out, int out_size, void* d_ws, size_t ws_size,
                              hipStream_t stream) {
    const float* x  = (const float*)d_in[0];
    const int* ei   = (const int*)d_in[1];
    const float* W1 = (const float*)d_in[2];
    const float* b1 = (const float*)d_in[3];
    const float* W2 = (const float*)d_in[4];
    const float* b2 = (const float*)d_in[5];
    float* out = (float*)d_out;

    const int N = in_sizes[0] / 128;
    const int E = in_sizes[1] / 2;
    const int* row = ei;       // edge_index[0] = source
    const int* col = ei + E;   // edge_index[1] = target

    char* p = (char*)d_ws;
    auto carve = [&](size_t bytes) -> void* {
        void* r = (void*)p;
        p += (bytes + 255) & ~(size_t)255;
        return r;
    };
    int*   cnt      = (int*)carve((size_t)N * 4);
    float* dinv     = (float*)carve((size_t)N * 4);
    int*   indptr   = (int*)carve((size_t)(N + 1) * 4);
    int*   bsum     = (int*)carve(512 * 4);
    int*   boff     = (int*)carve(512 * 4);
    int*   cursor   = (int*)carve((size_t)N * 4);
    int*   csr_row  = (int*)carve((size_t)E * 4);
    __hip_bfloat16* g1 = (__hip_bfloat16*)carve((size_t)N * 128 * 2);  // dinv*x@W1
    float* h1          = (float*)carve((size_t)N * 128 * 4);
    __hip_bfloat16* g2 = (__hip_bfloat16*)carve((size_t)N * 64 * 2);   // dinv*h1@W2

    const int NB = cdiv(N, 256);  // scan blocks (391 <= 512)
    const int AGG_BLOCKS = 2048;  // 8192 persistent waves, ~12 nodes each

    k_init<<<cdiv(N, 256), 256, 0, stream>>>(cnt, cursor, N);
    k_deg<<<cdiv(E, 256), 256, 0, stream>>>(col, cnt, E);
    k_dinv<<<cdiv(N, 256), 256, 0, stream>>>(cnt, dinv, N);
    k_scan1<<<NB, 256, 0, stream>>>(cnt, indptr, bsum, N);
    k_scan2<<<1, 512, 0, stream>>>(bsum, boff, NB);
    k_scan3<<<cdiv(N + 1, 256), 256, 0, stream>>>(indptr, boff, N, E);
    k_fill<<<cdiv(E, 256), 256, 0, stream>>>(row, col, indptr, cursor, csr_row, E);

    // layer 1: g1 = bf16(dinv * x@W1) ; h1 = relu(dinv*(g1_self+sum) + b1)
    gemm_k<128><<<cdiv(N, 32), 256, 0, stream>>>(x, W1, dinv, g1, N);
    k_agg128<<<AGG_BLOCKS, 256, 0, stream>>>(g1, indptr, csr_row, dinv, b1, h1, N);
    // layer 2: g2 = bf16(dinv * h1@W2) ; out = dinv*(g2_self+sum) + b2
    gemm_k<64><<<cdiv(N, 64), 256, 0, stream>>>(h1, W2, dinv, g2, N);
    k_agg64<<<AGG_BLOCKS, 256, 0, stream>>>(g2, indptr, csr_row, dinv, b2, out, N);
}